// Round 6
// baseline (233.054 us; speedup 1.0000x reference)
//
#include <hip/hip_runtime.h>
#include <math.h>

#define LENGTH 4096
#define BATCH  4096
#define NTHR   256           // 4 waves/block; each wave processes ONE full row
#define WPB    (NTHR / 64)   // 4 rows per block
#define GRID   (BATCH / WPB) // 1024 blocks = 4/CU -> whole grid resident
// per-thread: 64 timesteps, split into 8 segments of 8

typedef float vf4 __attribute__((ext_vector_type(4)));

// Raw barrier: make LDS ops visible + rendezvous WITHOUT draining vmcnt,
// so the in-flight obs loads survive the LUT-build barriers.
#define BAR() do {                                        \
    asm volatile("s_waitcnt lgkmcnt(0)" ::: "memory");    \
    __builtin_amdgcn_s_barrier();                         \
    asm volatile("" ::: "memory");                        \
  } while (0)

// max-plus 2x2 compose: D = A (x) B, D[k][l] = max_m A[k][m] + B[m][l]
__device__ __forceinline__ void mp_compose(
    float a00, float a01, float a10, float a11,
    float b00, float b01, float b10, float b11,
    float& d00, float& d01, float& d10, float& d11) {
  d00 = fmaxf(a00 + b00, a01 + b10);
  d01 = fmaxf(a00 + b01, a01 + b11);
  d10 = fmaxf(a10 + b00, a11 + b10);
  d11 = fmaxf(a10 + b01, a11 + b11);
}

// F <- (S (x) D_u) (x) F     (one timestep applied on the left)
__device__ __forceinline__ void mp_step(
    float& f00, float& f01, float& f10, float& f11, float ui, float q) {
  float a0l0 = f00 - ui, a1l0 = f10 + ui;
  float a0l1 = f01 - ui, a1l1 = f11 + ui;
  float n00 = fmaxf(a0l0 + q, a1l0 - q);
  float n10 = fmaxf(a0l0 - q, a1l0 + q);
  float n01 = fmaxf(a0l1 + q, a1l1 - q);
  float n11 = fmaxf(a0l1 - q, a1l1 + q);
  f00 = n00; f01 = n01; f10 = n10; f11 = n11;
}

__global__ __launch_bounds__(NTHR, 4) void chain_bp_kernel(
    const float* __restrict__ jp, const float* __restrict__ bp,
    const int* __restrict__ obs, float* __restrict__ out) {
  const int tid  = threadIdx.x;
  const int lane = tid & 63;
  const int wv   = tid >> 6;

  // All potentials pre-scaled by log2(e): outputs use raw v_exp_f32 (2^x).
  const float LOG2E = 1.44269504088896f;
  const float j  = jp[0];
  const float q  = 0.25f * j * LOG2E;      // log2 psi diag; off-diag = -q
  const float u0 = 0.5f * bp[0] * LOG2E;   // log2 phi[o=0][s=1] ; s=0 is -u
  const float u1 = 0.5f * bp[1] * LOG2E;
  const float wb = -fabsf(q);              // S (x) (wb,wb) == 0vec

  __shared__ vf4 lut4s[16];
  __shared__ vf4 lut8[256];

  const int row = blockIdx.x * WPB + wv;   // this wave's row
  const int t0  = lane * 64;               // this lane's first timestep

  // ---- load 64 obs (16 int4, imm offsets off one base) -> 64 packed bits ----
  // Issued before the LUT build; BAR() keeps them in flight across barriers.
  const int4* op = reinterpret_cast<const int4*>(obs + (size_t)row * LENGTH + t0);
  unsigned bits_lo = 0, bits_hi = 0;
#pragma unroll
  for (int k = 0; k < 8; ++k) {
    int4 o = op[k];
    unsigned nib = (o.x & 1) | ((o.y & 1) << 1) | ((o.z & 1) << 2) | ((o.w & 1) << 3);
    bits_lo |= nib << (4 * k);
  }
#pragma unroll
  for (int k = 0; k < 8; ++k) {
    int4 o = op[8 + k];
    unsigned nib = (o.x & 1) | ((o.y & 1) << 1) | ((o.z & 1) << 2) | ((o.w & 1) << 3);
    bits_hi |= nib << (4 * k);
  }

  // ---- build 4-bit LUT (16 threads), then 8-bit LUT (all 256 threads) ----
  if (tid < 16) {
    float ua = (tid & 1) ? u1 : u0;
    float f00 = -ua + q, f01 = ua - q, f10 = -ua - q, f11 = ua + q;
#pragma unroll
    for (int k = 1; k < 4; ++k)
      mp_step(f00, f01, f10, f11, ((tid >> k) & 1) ? u1 : u0, q);
    lut4s[tid] = (vf4){f00, f01, f10, f11};
  }
  BAR();
  {
    vf4 a = lut4s[tid >> 4], c = lut4s[tid & 15];
    float d00, d01, d10, d11;
    mp_compose(a[0], a[1], a[2], a[3], c[0], c[1], c[2], c[3], d00, d01, d10, d11);
    lut8[tid] = (vf4){d00, d01, d10, d11};
  }
  BAR();
  // ---- no further barriers: every wave is independent from here on ----

  // ---- 8 segment matrices (LDS gathers), thread chunk matrix F ----
  vf4 G[8];
#pragma unroll
  for (int s = 0; s < 4; ++s) G[s]     = lut8[(bits_lo >> (8 * s)) & 255];
#pragma unroll
  for (int s = 0; s < 4; ++s) G[4 + s] = lut8[(bits_hi >> (8 * s)) & 255];

  float f00 = G[0][0], f01 = G[0][1], f10 = G[0][2], f11 = G[0][3];
#pragma unroll
  for (int s = 1; s < 8; ++s) {
    float n00, n01, n10, n11;
    mp_compose(G[s][0], G[s][1], G[s][2], G[s][3], f00, f01, f10, f11,
               n00, n01, n10, n11);
    f00 = n00; f01 = n01; f10 = n10; f11 = n11;
  }

  // ---- wave scans over the 64 lane-chunks: prefix X, suffix Y of F^T ----
  float x00 = f00, x01 = f01, x10 = f10, x11 = f11;
  float y00 = f00, y01 = f10, y10 = f01, y11 = f11;  // transpose
#pragma unroll
  for (int d = 1; d < 64; d <<= 1) {
    float px00 = __shfl_up(x00, d), px01 = __shfl_up(x01, d);
    float px10 = __shfl_up(x10, d), px11 = __shfl_up(x11, d);
    float py00 = __shfl_down(y00, d), py01 = __shfl_down(y01, d);
    float py10 = __shfl_down(y10, d), py11 = __shfl_down(y11, d);
    if (lane >= d) {
      float n00, n01, n10, n11;
      mp_compose(x00, x01, x10, x11, px00, px01, px10, px11, n00, n01, n10, n11);
      x00 = n00; x01 = n01; x10 = n10; x11 = n11;
    }
    if (lane + d < 64) {
      float n00, n01, n10, n11;
      mp_compose(y00, y01, y10, y11, py00, py01, py10, py11, n00, n01, n10, n11);
      y00 = n00; y01 = n01; y10 = n10; y11 = n11;
    }
  }

  // f_in = forward vector at this lane's first step (row head = 0vec)
  float z0 = fmaxf(x00, x01);          // X (x) 0vec
  float z1 = fmaxf(x10, x11);
  float zp0 = __shfl_up(z0, 1), zp1 = __shfl_up(z1, 1);
  float fw0 = (lane == 0) ? 0.f : zp0;
  float fw1 = (lane == 0) ? 0.f : zp1;

  // w vector at this lane's chunk end (S-absorbable form; row tail = wb)
  float yv0 = fmaxf(y00 + wb, y01 + wb);
  float yv1 = fmaxf(y10 + wb, y11 + wb);
  float yn0 = __shfl_down(yv0, 1), yn1 = __shfl_down(yv1, 1);
  float wc0 = (lane == 63) ? wb : yn0;
  float wc1 = (lane == 63) ? wb : yn1;

  // ---- per-segment boundary w-vectors: w_{s-1} = G_s^T (x) w_s ----
  float wsa0[8], wsa1[8];
  wsa0[7] = wc0; wsa1[7] = wc1;
#pragma unroll
  for (int s = 7; s > 0; --s) {
    wsa0[s - 1] = fmaxf(G[s][0] + wsa0[s], G[s][2] + wsa1[s]);
    wsa1[s - 1] = fmaxf(G[s][1] + wsa0[s], G[s][3] + wsa1[s]);
  }

  // ---- per segment: local backward sweep, forward sweep + exp2 + stores ----
  float* outp = out + (size_t)row * (2 * LENGTH) + t0;
#pragma unroll
  for (int s = 0; s < 8; ++s) {
    unsigned byte = ((s < 4) ? (bits_lo >> (8 * s)) : (bits_hi >> (8 * (s - 4)))) & 255;
    float us[8];
#pragma unroll
    for (int i = 0; i < 8; ++i) us[i] = ((byte >> i) & 1) ? u1 : u0;

    // backward at last step of segment: e = S (x) w_s
    float b0[8], b1[8];
    b0[7] = fmaxf( q + wsa0[s], -q + wsa1[s]);
    b1[7] = fmaxf(-q + wsa0[s],  q + wsa1[s]);
#pragma unroll
    for (int i = 7; i > 0; --i) {
      float a0 = b0[i] - us[i], a1 = b1[i] + us[i];
      b0[i - 1] = fmaxf(a0 + q, a1 - q);
      b1[i - 1] = fmaxf(a0 - q, a1 + q);
    }

    vf4 p0lo, p0hi, p1lo, p1hi;
#pragma unroll
    for (int i = 0; i < 8; ++i) {
      float e0 = __builtin_amdgcn_exp2f(-us[i] + fw0 + b0[i]);
      float e1 = __builtin_amdgcn_exp2f( us[i] + fw1 + b1[i]);
      if (i < 4) { p0lo[i] = e0; p1lo[i] = e1; }
      else       { p0hi[i - 4] = e0; p1hi[i - 4] = e1; }
      float a0 = fw0 - us[i], a1 = fw1 + us[i];   // fw carries into next segment
      fw0 = fmaxf(a0 + q, a1 - q);
      fw1 = fmaxf(a0 - q, a1 + q);
    }
    *reinterpret_cast<vf4*>(outp + 8 * s)              = p0lo;
    *reinterpret_cast<vf4*>(outp + 8 * s + 4)          = p0hi;
    *reinterpret_cast<vf4*>(outp + LENGTH + 8 * s)     = p1lo;
    *reinterpret_cast<vf4*>(outp + LENGTH + 8 * s + 4) = p1hi;
  }
}

extern "C" void kernel_launch(void* const* d_in, const int* in_sizes, int n_in,
                              void* d_out, int out_size, void* d_ws, size_t ws_size,
                              hipStream_t stream) {
  const float* jp  = (const float*)d_in[0];   // scalar j
  const float* bp  = (const float*)d_in[1];   // b[2]
  const int*   obs = (const int*)d_in[2];     // [BATCH, LENGTH] int32
  float* out = (float*)d_out;                 // [BATCH, 2, LENGTH] fp32

  chain_bp_kernel<<<GRID, NTHR, 0, stream>>>(jp, bp, obs, out);
}

// Round 7
// 222.340 us; speedup vs baseline: 1.0482x; 1.0482x over previous
//
#include <hip/hip_runtime.h>
#include <math.h>

#define LENGTH 4096
#define BATCH  4096
#define CHUNK  8       // timesteps per thread
#define NTHR   512     // threads per block; NTHR*CHUNK == LENGTH (one row slice)
#define NWAVE  (NTHR / 64)   // 8
#define RPB    2       // rows per block, scans interleaved for ILP
#define GRID   (BATCH / RPB) // 2048 fresh blocks (no persistence)

typedef float vf4 __attribute__((ext_vector_type(4)));

// Raw barrier: make LDS ops visible + rendezvous WITHOUT draining vmcnt,
// so the up-front obs loads stay in flight across the LUT-build barriers.
#define BAR() do {                                        \
    asm volatile("s_waitcnt lgkmcnt(0)" ::: "memory");    \
    __builtin_amdgcn_s_barrier();                         \
    asm volatile("" ::: "memory");                        \
  } while (0)

// max-plus 2x2 compose: D = A (x) B, D[k][l] = max_m A[k][m] + B[m][l]
__device__ __forceinline__ void mp_compose(
    float a00, float a01, float a10, float a11,
    float b00, float b01, float b10, float b11,
    float& d00, float& d01, float& d10, float& d11) {
  d00 = fmaxf(a00 + b00, a01 + b10);
  d01 = fmaxf(a00 + b01, a01 + b11);
  d10 = fmaxf(a10 + b00, a11 + b10);
  d11 = fmaxf(a10 + b01, a11 + b11);
}

// F <- (S (x) D_u) (x) F     (one timestep applied on the left)
__device__ __forceinline__ void mp_step(
    float& f00, float& f01, float& f10, float& f11, float ui, float q) {
  float a0l0 = f00 - ui, a1l0 = f10 + ui;
  float a0l1 = f01 - ui, a1l1 = f11 + ui;
  float n00 = fmaxf(a0l0 + q, a1l0 - q);
  float n10 = fmaxf(a0l0 - q, a1l0 + q);
  float n01 = fmaxf(a0l1 + q, a1l1 - q);
  float n11 = fmaxf(a0l1 - q, a1l1 + q);
  f00 = n00; f01 = n01; f10 = n10; f11 = n11;
}

// Per-row epilogue: stitch (reads LDS written before the barrier), in-chunk
// backward + forward sweeps, exp2 beliefs, R0-style coalesced stores.
__device__ __forceinline__ void row_epilogue(
    float x00, float x01, float x10, float x11,
    float y00, float y01, float y10, float y11,
    int idx, const float (*smpR)[4], const float (*smsR)[4],
    float* __restrict__ outp, int wv, int lane,
    float q, float u0, float u1, float wb) {
  // fhead = W_{wv-1} (x) ... (x) W_0 (x) 0vec
  float fh0 = 0.f, fh1 = 0.f;
  for (int k = 0; k < wv; ++k) {
    float m00 = smpR[k][0], m01 = smpR[k][1], m10 = smpR[k][2], m11 = smpR[k][3];
    float n0 = fmaxf(m00 + fh0, m01 + fh1);
    float n1 = fmaxf(m10 + fh0, m11 + fh1);
    fh0 = n0; fh1 = n1;
  }
  // wtail = V_{wv+1} (x) ... (x) V_{NWAVE-1} (x) w_base
  float wt0 = wb, wt1 = wb;
  for (int k = NWAVE - 1; k > wv; --k) {
    float m00 = smsR[k][0], m01 = smsR[k][1], m10 = smsR[k][2], m11 = smsR[k][3];
    float n0 = fmaxf(m00 + wt0, m01 + wt1);
    float n1 = fmaxf(m10 + wt0, m11 + wt1);
    wt0 = n0; wt1 = n1;
  }

  // z_c = X_c (x) fhead; f_in = z_{c-1}
  float z0 = fmaxf(x00 + fh0, x01 + fh1);
  float z1 = fmaxf(x10 + fh0, x11 + fh1);
  float zp0 = __shfl_up(z0, 1), zp1 = __shfl_up(z1, 1);
  float fw0 = (lane == 0) ? fh0 : zp0;
  float fw1 = (lane == 0) ? fh1 : zp1;

  // y_c = Y_c (x) wtail; w_c = y_{c+1} (lane 63 -> wtail); g = S (x) w_c
  float yv0 = fmaxf(y00 + wt0, y01 + wt1);
  float yv1 = fmaxf(y10 + wt0, y11 + wt1);
  float yn0 = __shfl_down(yv0, 1), yn1 = __shfl_down(yv1, 1);
  float wc0 = (lane == 63) ? wt0 : yn0;
  float wc1 = (lane == 63) ? wt1 : yn1;
  float g0 = fmaxf(q + wc0, -q + wc1);
  float g1 = fmaxf(-q + wc0, q + wc1);

  float u[CHUNK];
#pragma unroll
  for (int i = 0; i < CHUNK; ++i) u[i] = ((idx >> i) & 1) ? u1 : u0;

  // in-chunk backward sweep
  float b0[CHUNK], b1[CHUNK];
  b0[CHUNK - 1] = g0; b1[CHUNK - 1] = g1;
#pragma unroll
  for (int i = CHUNK - 1; i > 0; --i) {
    float a0 = b0[i] - u[i], a1 = b1[i] + u[i];
    b0[i - 1] = fmaxf(a0 + q, a1 - q);
    b1[i - 1] = fmaxf(a0 - q, a1 + q);
  }

  // in-chunk forward sweep + belief (exp2); four 16B coalesced stores
  vf4 p0lo, p0hi, p1lo, p1hi;
#pragma unroll
  for (int i = 0; i < CHUNK; ++i) {
    float e0 = __builtin_amdgcn_exp2f(-u[i] + fw0 + b0[i]);
    float e1 = __builtin_amdgcn_exp2f( u[i] + fw1 + b1[i]);
    if (i < 4) { p0lo[i] = e0; p1lo[i] = e1; }
    else       { p0hi[i - 4] = e0; p1hi[i - 4] = e1; }
    float a0 = fw0 - u[i], a1 = fw1 + u[i];
    fw0 = fmaxf(a0 + q, a1 - q);
    fw1 = fmaxf(a0 - q, a1 + q);
  }
  *reinterpret_cast<vf4*>(outp)              = p0lo;
  *reinterpret_cast<vf4*>(outp + 4)          = p0hi;
  *reinterpret_cast<vf4*>(outp + LENGTH)     = p1lo;
  *reinterpret_cast<vf4*>(outp + LENGTH + 4) = p1hi;
}

__global__ __launch_bounds__(NTHR, 8) void chain_bp_kernel(
    const float* __restrict__ jp, const float* __restrict__ bp,
    const int* __restrict__ obs, float* __restrict__ out) {
  const int tid  = threadIdx.x;
  const int lane = tid & 63;
  const int wv   = tid >> 6;

  // All potentials pre-scaled by log2(e): outputs use raw v_exp_f32 (2^x).
  const float LOG2E = 1.44269504088896f;
  const float j  = jp[0];
  const float q  = 0.25f * j * LOG2E;      // log2 psi diag; off-diag = -q
  const float u0 = 0.5f * bp[0] * LOG2E;   // log2 phi[o=0][s=1] ; s=0 is -u
  const float u1 = 0.5f * bp[1] * LOG2E;
  const float wb = -fabsf(q);              // S (x) (wb,wb) == 0vec

  __shared__ vf4 lut4s[16];
  __shared__ vf4 lut8[256];
  __shared__ float smp[RPB][NWAVE][4];
  __shared__ float sms[RPB][NWAVE][4];

  const int rowA = blockIdx.x * RPB;
  const int t0   = tid * CHUNK;

  // ---- issue BOTH rows' obs loads up front (4 coalesced int4 loads) ----
  const int4* pA = reinterpret_cast<const int4*>(obs + (size_t)rowA * LENGTH + t0);
  const int4* pB = reinterpret_cast<const int4*>(obs + (size_t)(rowA + 1) * LENGTH + t0);
  int4 a0 = pA[0], a1 = pA[1];
  int4 c0 = pB[0], c1 = pB[1];

  // ---- build 4-bit LUT (16 threads), then 8-bit LUT (256 threads) ----
  // Overlaps the in-flight obs loads (BAR does not drain vmcnt).
  if (tid < 16) {
    float ua = (tid & 1) ? u1 : u0;
    float f00 = -ua + q, f01 = ua - q, f10 = -ua - q, f11 = ua + q;
#pragma unroll
    for (int k = 1; k < 4; ++k)
      mp_step(f00, f01, f10, f11, ((tid >> k) & 1) ? u1 : u0, q);
    lut4s[tid] = (vf4){f00, f01, f10, f11};
  }
  BAR();
  if (tid < 256) {
    vf4 a = lut4s[tid >> 4], c = lut4s[tid & 15];
    float d00, d01, d10, d11;
    mp_compose(a[0], a[1], a[2], a[3], c[0], c[1], c[2], c[3], d00, d01, d10, d11);
    lut8[tid] = (vf4){d00, d01, d10, d11};
  }
  BAR();

  // ---- chunk matrices for both rows (two ds_read_b128 gathers) ----
  int idxA = a0.x | (a0.y<<1) | (a0.z<<2) | (a0.w<<3)
           | (a1.x<<4) | (a1.y<<5) | (a1.z<<6) | (a1.w<<7);
  int idxB = c0.x | (c0.y<<1) | (c0.z<<2) | (c0.w<<3)
           | (c1.x<<4) | (c1.y<<5) | (c1.z<<6) | (c1.w<<7);
  vf4 FA = lut8[idxA];
  vf4 FB = lut8[idxB];

  // ---- interleaved wave scans for BOTH rows: 4 independent chains ----
  float xA00 = FA[0], xA01 = FA[1], xA10 = FA[2], xA11 = FA[3];
  float yA00 = FA[0], yA01 = FA[2], yA10 = FA[1], yA11 = FA[3];  // transpose
  float xB00 = FB[0], xB01 = FB[1], xB10 = FB[2], xB11 = FB[3];
  float yB00 = FB[0], yB01 = FB[2], yB10 = FB[1], yB11 = FB[3];
#pragma unroll
  for (int d = 1; d < 64; d <<= 1) {
    float pA00 = __shfl_up(xA00, d), pA01 = __shfl_up(xA01, d);
    float pA10 = __shfl_up(xA10, d), pA11 = __shfl_up(xA11, d);
    float qA00 = __shfl_down(yA00, d), qA01 = __shfl_down(yA01, d);
    float qA10 = __shfl_down(yA10, d), qA11 = __shfl_down(yA11, d);
    float pB00 = __shfl_up(xB00, d), pB01 = __shfl_up(xB01, d);
    float pB10 = __shfl_up(xB10, d), pB11 = __shfl_up(xB11, d);
    float qB00 = __shfl_down(yB00, d), qB01 = __shfl_down(yB01, d);
    float qB10 = __shfl_down(yB10, d), qB11 = __shfl_down(yB11, d);
    if (lane >= d) {
      float n00, n01, n10, n11;
      mp_compose(xA00, xA01, xA10, xA11, pA00, pA01, pA10, pA11, n00, n01, n10, n11);
      xA00 = n00; xA01 = n01; xA10 = n10; xA11 = n11;
      mp_compose(xB00, xB01, xB10, xB11, pB00, pB01, pB10, pB11, n00, n01, n10, n11);
      xB00 = n00; xB01 = n01; xB10 = n10; xB11 = n11;
    }
    if (lane + d < 64) {
      float n00, n01, n10, n11;
      mp_compose(yA00, yA01, yA10, yA11, qA00, qA01, qA10, qA11, n00, n01, n10, n11);
      yA00 = n00; yA01 = n01; yA10 = n10; yA11 = n11;
      mp_compose(yB00, yB01, yB10, yB11, qB00, qB01, qB10, qB11, n00, n01, n10, n11);
      yB00 = n00; yB01 = n01; yB10 = n10; yB11 = n11;
    }
  }

  // ---- stitch both rows with ONE barrier ----
  if (lane == 63) {
    smp[0][wv][0] = xA00; smp[0][wv][1] = xA01; smp[0][wv][2] = xA10; smp[0][wv][3] = xA11;
    smp[1][wv][0] = xB00; smp[1][wv][1] = xB01; smp[1][wv][2] = xB10; smp[1][wv][3] = xB11;
  }
  if (lane == 0) {
    sms[0][wv][0] = yA00; sms[0][wv][1] = yA01; sms[0][wv][2] = yA10; sms[0][wv][3] = yA11;
    sms[1][wv][0] = yB00; sms[1][wv][1] = yB01; sms[1][wv][2] = yB10; sms[1][wv][3] = yB11;
  }
  BAR();

  // ---- per-row epilogues (R0-proven math; coalesced stores) ----
  float* outA = out + (size_t)rowA * (2 * LENGTH) + t0;
  row_epilogue(xA00, xA01, xA10, xA11, yA00, yA01, yA10, yA11,
               idxA, smp[0], sms[0], outA, wv, lane, q, u0, u1, wb);
  float* outB = out + (size_t)(rowA + 1) * (2 * LENGTH) + t0;
  row_epilogue(xB00, xB01, xB10, xB11, yB00, yB01, yB10, yB11,
               idxB, smp[1], sms[1], outB, wv, lane, q, u0, u1, wb);
}

extern "C" void kernel_launch(void* const* d_in, const int* in_sizes, int n_in,
                              void* d_out, int out_size, void* d_ws, size_t ws_size,
                              hipStream_t stream) {
  const float* jp  = (const float*)d_in[0];   // scalar j
  const float* bp  = (const float*)d_in[1];   // b[2]
  const int*   obs = (const int*)d_in[2];     // [BATCH, LENGTH] int32
  float* out = (float*)d_out;                 // [BATCH, 2, LENGTH] fp32

  chain_bp_kernel<<<GRID, NTHR, 0, stream>>>(jp, bp, obs, out);
}

// Round 8
// 190.230 us; speedup vs baseline: 1.2251x; 1.1688x over previous
//
#include <hip/hip_runtime.h>
#include <math.h>

#define LENGTH 4096
#define BATCH  4096
#define CHUNK  8       // timesteps per thread
#define NTHR   512     // threads per block; NTHR*CHUNK == LENGTH (one row slice)
#define NWAVE  (NTHR / 64)   // 8
#define RPB    2       // rows per block, scans interleaved for ILP
#define GRID   (BATCH / RPB) // 2048 fresh blocks (no persistence)

typedef float vf4 __attribute__((ext_vector_type(4)));

// Raw barrier: make LDS ops visible + rendezvous WITHOUT draining vmcnt,
// so the up-front obs loads stay in flight across the LUT-build barriers.
#define BAR() do {                                        \
    asm volatile("s_waitcnt lgkmcnt(0)" ::: "memory");    \
    __builtin_amdgcn_s_barrier();                         \
    asm volatile("" ::: "memory");                        \
  } while (0)

// max-plus 2x2 compose: D = A (x) B, D[k][l] = max_m A[k][m] + B[m][l]
__device__ __forceinline__ void mp_compose(
    float a00, float a01, float a10, float a11,
    float b00, float b01, float b10, float b11,
    float& d00, float& d01, float& d10, float& d11) {
  d00 = fmaxf(a00 + b00, a01 + b10);
  d01 = fmaxf(a00 + b01, a01 + b11);
  d10 = fmaxf(a10 + b00, a11 + b10);
  d11 = fmaxf(a10 + b01, a11 + b11);
}

// F <- (S (x) D_u) (x) F     (one timestep applied on the left)
__device__ __forceinline__ void mp_step(
    float& f00, float& f01, float& f10, float& f11, float ui, float q) {
  float a0l0 = f00 - ui, a1l0 = f10 + ui;
  float a0l1 = f01 - ui, a1l1 = f11 + ui;
  float n00 = fmaxf(a0l0 + q, a1l0 - q);
  float n10 = fmaxf(a0l0 - q, a1l0 + q);
  float n01 = fmaxf(a0l1 + q, a1l1 - q);
  float n11 = fmaxf(a0l1 - q, a1l1 + q);
  f00 = n00; f01 = n01; f10 = n10; f11 = n11;
}

// Per-row epilogue: stitch (reads LDS written before the barrier), in-chunk
// backward + forward sweeps, exp2 beliefs, coalesced stores.
__device__ __forceinline__ void row_epilogue(
    float x00, float x01, float x10, float x11,
    float y00, float y01, float y10, float y11,
    int idx, const float (*smpR)[4], const float (*smsR)[4],
    float* __restrict__ outp, int wv, int lane,
    float q, float u0, float u1, float wb) {
  // fhead = W_{wv-1} (x) ... (x) W_0 (x) 0vec
  float fh0 = 0.f, fh1 = 0.f;
  for (int k = 0; k < wv; ++k) {
    float m00 = smpR[k][0], m01 = smpR[k][1], m10 = smpR[k][2], m11 = smpR[k][3];
    float n0 = fmaxf(m00 + fh0, m01 + fh1);
    float n1 = fmaxf(m10 + fh0, m11 + fh1);
    fh0 = n0; fh1 = n1;
  }
  // wtail = V_{wv+1} (x) ... (x) V_{NWAVE-1} (x) w_base
  float wt0 = wb, wt1 = wb;
  for (int k = NWAVE - 1; k > wv; --k) {
    float m00 = smsR[k][0], m01 = smsR[k][1], m10 = smsR[k][2], m11 = smsR[k][3];
    float n0 = fmaxf(m00 + wt0, m01 + wt1);
    float n1 = fmaxf(m10 + wt0, m11 + wt1);
    wt0 = n0; wt1 = n1;
  }

  // z_c = X_c (x) fhead; f_in = z_{c-1}
  float z0 = fmaxf(x00 + fh0, x01 + fh1);
  float z1 = fmaxf(x10 + fh0, x11 + fh1);
  float zp0 = __shfl_up(z0, 1), zp1 = __shfl_up(z1, 1);
  float fw0 = (lane == 0) ? fh0 : zp0;
  float fw1 = (lane == 0) ? fh1 : zp1;

  // y_c = Y_c (x) wtail; w_c = y_{c+1} (lane 63 -> wtail); g = S (x) w_c
  float yv0 = fmaxf(y00 + wt0, y01 + wt1);
  float yv1 = fmaxf(y10 + wt0, y11 + wt1);
  float yn0 = __shfl_down(yv0, 1), yn1 = __shfl_down(yv1, 1);
  float wc0 = (lane == 63) ? wt0 : yn0;
  float wc1 = (lane == 63) ? wt1 : yn1;
  float g0 = fmaxf(q + wc0, -q + wc1);
  float g1 = fmaxf(-q + wc0, q + wc1);

  float u[CHUNK];
#pragma unroll
  for (int i = 0; i < CHUNK; ++i) u[i] = ((idx >> i) & 1) ? u1 : u0;

  // in-chunk backward sweep
  float b0[CHUNK], b1[CHUNK];
  b0[CHUNK - 1] = g0; b1[CHUNK - 1] = g1;
#pragma unroll
  for (int i = CHUNK - 1; i > 0; --i) {
    float a0 = b0[i] - u[i], a1 = b1[i] + u[i];
    b0[i - 1] = fmaxf(a0 + q, a1 - q);
    b1[i - 1] = fmaxf(a0 - q, a1 + q);
  }

  // in-chunk forward sweep + belief (exp2); four 16B coalesced stores
  vf4 p0lo, p0hi, p1lo, p1hi;
#pragma unroll
  for (int i = 0; i < CHUNK; ++i) {
    float e0 = __builtin_amdgcn_exp2f(-u[i] + fw0 + b0[i]);
    float e1 = __builtin_amdgcn_exp2f( u[i] + fw1 + b1[i]);
    if (i < 4) { p0lo[i] = e0; p1lo[i] = e1; }
    else       { p0hi[i - 4] = e0; p1hi[i - 4] = e1; }
    float a0 = fw0 - u[i], a1 = fw1 + u[i];
    fw0 = fmaxf(a0 + q, a1 - q);
    fw1 = fmaxf(a0 - q, a1 + q);
  }
  *reinterpret_cast<vf4*>(outp)              = p0lo;
  *reinterpret_cast<vf4*>(outp + 4)          = p0hi;
  *reinterpret_cast<vf4*>(outp + LENGTH)     = p1lo;
  *reinterpret_cast<vf4*>(outp + LENGTH + 4) = p1hi;
}

// (512, 4): 4 waves/EU floor -> 128-VGPR cap. The previous (512, 8) capped
// at 64 VGPRs and SPILLED (VGPR_Count=32, scratch traffic inflated
// WRITE_SIZE to 242 MB / FETCH to 88 MB). 16 waves/CU + dual-row ILP
// covers latency without spills.
__global__ __launch_bounds__(NTHR, 4) void chain_bp_kernel(
    const float* __restrict__ jp, const float* __restrict__ bp,
    const int* __restrict__ obs, float* __restrict__ out) {
  const int tid  = threadIdx.x;
  const int lane = tid & 63;
  const int wv   = tid >> 6;

  // All potentials pre-scaled by log2(e): outputs use raw v_exp_f32 (2^x).
  const float LOG2E = 1.44269504088896f;
  const float j  = jp[0];
  const float q  = 0.25f * j * LOG2E;      // log2 psi diag; off-diag = -q
  const float u0 = 0.5f * bp[0] * LOG2E;   // log2 phi[o=0][s=1] ; s=0 is -u
  const float u1 = 0.5f * bp[1] * LOG2E;
  const float wb = -fabsf(q);              // S (x) (wb,wb) == 0vec

  __shared__ vf4 lut4s[16];
  __shared__ vf4 lut8[256];
  __shared__ float smp[RPB][NWAVE][4];
  __shared__ float sms[RPB][NWAVE][4];

  const int rowA = blockIdx.x * RPB;
  const int t0   = tid * CHUNK;

  // ---- issue BOTH rows' obs loads up front (4 coalesced int4 loads) ----
  const int4* pA = reinterpret_cast<const int4*>(obs + (size_t)rowA * LENGTH + t0);
  const int4* pB = reinterpret_cast<const int4*>(obs + (size_t)(rowA + 1) * LENGTH + t0);
  int4 a0 = pA[0], a1 = pA[1];
  int4 c0 = pB[0], c1 = pB[1];

  // ---- build 4-bit LUT (16 threads), then 8-bit LUT (256 threads) ----
  // Overlaps the in-flight obs loads (BAR does not drain vmcnt).
  if (tid < 16) {
    float ua = (tid & 1) ? u1 : u0;
    float f00 = -ua + q, f01 = ua - q, f10 = -ua - q, f11 = ua + q;
#pragma unroll
    for (int k = 1; k < 4; ++k)
      mp_step(f00, f01, f10, f11, ((tid >> k) & 1) ? u1 : u0, q);
    lut4s[tid] = (vf4){f00, f01, f10, f11};
  }
  BAR();
  if (tid < 256) {
    vf4 a = lut4s[tid >> 4], c = lut4s[tid & 15];
    float d00, d01, d10, d11;
    mp_compose(a[0], a[1], a[2], a[3], c[0], c[1], c[2], c[3], d00, d01, d10, d11);
    lut8[tid] = (vf4){d00, d01, d10, d11};
  }
  BAR();

  // ---- chunk matrices for both rows (two ds_read_b128 gathers) ----
  int idxA = a0.x | (a0.y<<1) | (a0.z<<2) | (a0.w<<3)
           | (a1.x<<4) | (a1.y<<5) | (a1.z<<6) | (a1.w<<7);
  int idxB = c0.x | (c0.y<<1) | (c0.z<<2) | (c0.w<<3)
           | (c1.x<<4) | (c1.y<<5) | (c1.z<<6) | (c1.w<<7);
  vf4 FA = lut8[idxA];
  vf4 FB = lut8[idxB];

  // ---- interleaved wave scans for BOTH rows: 4 independent chains ----
  float xA00 = FA[0], xA01 = FA[1], xA10 = FA[2], xA11 = FA[3];
  float yA00 = FA[0], yA01 = FA[2], yA10 = FA[1], yA11 = FA[3];  // transpose
  float xB00 = FB[0], xB01 = FB[1], xB10 = FB[2], xB11 = FB[3];
  float yB00 = FB[0], yB01 = FB[2], yB10 = FB[1], yB11 = FB[3];
#pragma unroll
  for (int d = 1; d < 64; d <<= 1) {
    float pA00 = __shfl_up(xA00, d), pA01 = __shfl_up(xA01, d);
    float pA10 = __shfl_up(xA10, d), pA11 = __shfl_up(xA11, d);
    float qA00 = __shfl_down(yA00, d), qA01 = __shfl_down(yA01, d);
    float qA10 = __shfl_down(yA10, d), qA11 = __shfl_down(yA11, d);
    float pB00 = __shfl_up(xB00, d), pB01 = __shfl_up(xB01, d);
    float pB10 = __shfl_up(xB10, d), pB11 = __shfl_up(xB11, d);
    float qB00 = __shfl_down(yB00, d), qB01 = __shfl_down(yB01, d);
    float qB10 = __shfl_down(yB10, d), qB11 = __shfl_down(yB11, d);
    if (lane >= d) {
      float n00, n01, n10, n11;
      mp_compose(xA00, xA01, xA10, xA11, pA00, pA01, pA10, pA11, n00, n01, n10, n11);
      xA00 = n00; xA01 = n01; xA10 = n10; xA11 = n11;
      mp_compose(xB00, xB01, xB10, xB11, pB00, pB01, pB10, pB11, n00, n01, n10, n11);
      xB00 = n00; xB01 = n01; xB10 = n10; xB11 = n11;
    }
    if (lane + d < 64) {
      float n00, n01, n10, n11;
      mp_compose(yA00, yA01, yA10, yA11, qA00, qA01, qA10, qA11, n00, n01, n10, n11);
      yA00 = n00; yA01 = n01; yA10 = n10; yA11 = n11;
      mp_compose(yB00, yB01, yB10, yB11, qB00, qB01, qB10, qB11, n00, n01, n10, n11);
      yB00 = n00; yB01 = n01; yB10 = n10; yB11 = n11;
    }
  }

  // ---- stitch both rows with ONE barrier ----
  if (lane == 63) {
    smp[0][wv][0] = xA00; smp[0][wv][1] = xA01; smp[0][wv][2] = xA10; smp[0][wv][3] = xA11;
    smp[1][wv][0] = xB00; smp[1][wv][1] = xB01; smp[1][wv][2] = xB10; smp[1][wv][3] = xB11;
  }
  if (lane == 0) {
    sms[0][wv][0] = yA00; sms[0][wv][1] = yA01; sms[0][wv][2] = yA10; sms[0][wv][3] = yA11;
    sms[1][wv][0] = yB00; sms[1][wv][1] = yB01; sms[1][wv][2] = yB10; sms[1][wv][3] = yB11;
  }
  BAR();

  // ---- per-row epilogues (coalesced stores) ----
  float* outA = out + (size_t)rowA * (2 * LENGTH) + t0;
  row_epilogue(xA00, xA01, xA10, xA11, yA00, yA01, yA10, yA11,
               idxA, smp[0], sms[0], outA, wv, lane, q, u0, u1, wb);
  float* outB = out + (size_t)(rowA + 1) * (2 * LENGTH) + t0;
  row_epilogue(xB00, xB01, xB10, xB11, yB00, yB01, yB10, yB11,
               idxB, smp[1], sms[1], outB, wv, lane, q, u0, u1, wb);
}

extern "C" void kernel_launch(void* const* d_in, const int* in_sizes, int n_in,
                              void* d_out, int out_size, void* d_ws, size_t ws_size,
                              hipStream_t stream) {
  const float* jp  = (const float*)d_in[0];   // scalar j
  const float* bp  = (const float*)d_in[1];   // b[2]
  const int*   obs = (const int*)d_in[2];     // [BATCH, LENGTH] int32
  float* out = (float*)d_out;                 // [BATCH, 2, LENGTH] fp32

  chain_bp_kernel<<<GRID, NTHR, 0, stream>>>(jp, bp, obs, out);
}